// Round 18
// baseline (452.890 us; speedup 1.0000x reference)
//
#include <hip/hip_runtime.h>
#include <math.h>

// Chamfer distance, B=4, N=M=8192, fp32. Semantics validated R15-R17.
// d_out (f32): dist1[B*N] | dist2[B*M] | idx1[B*N] | idx2[B*M]
//
// Exact per-pair math (no FMA, validated):
//   qq = (qx*qx+qy*qy)+qz*qz ; tt likewise (prep kernel)
//   e  = (qz*z+qy*y)+qx*x    ; sq = (qq+tt)-2e ; d = sqrtf(max(sq,0))
// Track FIRST and LAST index of min-d; idx = (last-first>1200)?last:first.
//
// R18: no LDS in hot loop. Prep kernel packs {x,y,z,tt} float4 arrays in ws;
// main kernel streams them with wave-uniform loads (scalar/L1-broadcast).

#define BATCH 4
#define NPTS  8192
#define QB    64
#define NSLICE 4
#define SLICE 2048              // targets per wave slice

__global__ __launch_bounds__(256)
void prep_k(const float* __restrict__ xyz1,
            const float* __restrict__ xyz2,
            float4* __restrict__ pk) {
#pragma clang fp contract(off)
    int tid = blockIdx.x * blockDim.x + threadIdx.x;   // 0..65535
    int src = tid >> 15;                               // 0: xyz1, 1: xyz2
    int b   = (tid >> 13) & 3;
    int i   = tid & (NPTS - 1);
    const float* p = (src == 0 ? xyz1 : xyz2) + ((size_t)b * NPTS + i) * 3;
    float x = p[0], y = p[1], z = p[2];
    float tt = __fadd_rn(__fadd_rn(__fmul_rn(x, x), __fmul_rn(y, y)),
                         __fmul_rn(z, z));
    pk[tid] = make_float4(x, y, z, tt);                // layout (src*4+b)*NPTS+i
}

__global__ __launch_bounds__(256, 4)
void chamfer_main(const float4* __restrict__ pk, float* __restrict__ out) {
#pragma clang fp contract(off)
    __shared__ float red_d[NSLICE][QB];
    __shared__ int   red_f[NSLICE][QB];
    __shared__ int   red_l[NSLICE][QB];

    int bid = blockIdx.x;                  // dir*512 + b*128 + qg
    int dir = bid >> 9;
    int rem = bid & 511;
    int b   = rem >> 7;
    int qg  = rem & 127;

    int t     = threadIdx.x;
    int lane  = t & (QB - 1);
    int slice = t >> 6;

    // query: {x,y,z,qq} from pk (qq precomputed in validated order)
    const float4* qkp = pk + ((size_t)((dir == 0 ? 0 : 1) * BATCH + b) * NPTS);
    const float4* tp  = pk + ((size_t)((dir == 0 ? 1 : 0) * BATCH + b) * NPTS);

    int qi = qg * QB + lane;
    float4 qv = qkp[qi];
    float qx = qv.x, qy = qv.y, qz = qv.z, qq = qv.w;

    float bd0 = INFINITY, bd1 = INFINITY, bd2 = INFINITY, bd3 = INFINITY;
    int f0 = 0, f1 = 0, f2 = 0, f3 = 0;
    int l0 = 0, l1 = 0, l2 = 0, l3 = 0;

    const int jb0 = slice * SLICE;

    for (int jj = 0; jj < SLICE; jj += 8) {
        int jb = jb0 + jj;
        // 8 wave-uniform float4 loads (128 B), hoisted by compiler
        float4 v0 = tp[jb + 0];
        float4 v1 = tp[jb + 1];
        float4 v2 = tp[jb + 2];
        float4 v3 = tp[jb + 3];
        float4 v4 = tp[jb + 4];
        float4 v5 = tp[jb + 5];
        float4 v6 = tp[jb + 6];
        float4 v7 = tp[jb + 7];

        // pair p: points (2p, 2p+1) -> residue p  (validated op sequence)
        #define PAIR(va, vb, BD, FF, LL)                                        \
        {                                                                       \
            float m1x = __fmul_rn(qz, va.z), m1y = __fmul_rn(qz, vb.z);         \
            float m2x = __fmul_rn(qy, va.y), m2y = __fmul_rn(qy, vb.y);         \
            float a1x = __fadd_rn(m1x, m2x), a1y = __fadd_rn(m1y, m2y);         \
            float m3x = __fmul_rn(qx, va.x), m3y = __fmul_rn(qx, vb.x);         \
            float ex  = __fadd_rn(a1x, m3x), ey  = __fadd_rn(a1y, m3y);         \
            float sx  = __fadd_rn(qq, va.w), sy  = __fadd_rn(qq, vb.w);         \
            float e2x = __fadd_rn(ex, ex),   e2y = __fadd_rn(ey, ey);           \
            float qsx = __fsub_rn(sx, e2x),  qsy = __fsub_rn(sy, e2y);          \
            float cx  = fmaxf(qsx, 0.0f),    cy  = fmaxf(qsy, 0.0f);            \
            float d0_ = sqrtf(cx),           d1_ = sqrtf(cy);                   \
            bool lt = d0_ < BD, le = d0_ <= BD;                                 \
            FF = lt ? j0_ : FF; LL = le ? j0_ : LL; BD = fminf(BD, d0_);        \
            lt = d1_ < BD; le = d1_ <= BD;                                      \
            FF = lt ? j1_ : FF; LL = le ? j1_ : LL; BD = fminf(BD, d1_);        \
        }

        { int j0_ = jb + 0, j1_ = jb + 1; PAIR(v0, v1, bd0, f0, l0) }
        { int j0_ = jb + 2, j1_ = jb + 3; PAIR(v2, v3, bd1, f1, l1) }
        { int j0_ = jb + 4, j1_ = jb + 5; PAIR(v4, v5, bd2, f2, l2) }
        { int j0_ = jb + 6, j1_ = jb + 7; PAIR(v6, v7, bd3, f3, l3) }
        #undef PAIR
    }

    // merge 4 residues (union semantics, validated)
    float bd = fminf(fminf(bd0, bd1), fminf(bd2, bd3));
    int fi = 0x7FFFFFFF, la = -1;
    if (bd0 == bd) { fi = min(fi, f0); la = max(la, l0); }
    if (bd1 == bd) { fi = min(fi, f1); la = max(la, l1); }
    if (bd2 == bd) { fi = min(fi, f2); la = max(la, l2); }
    if (bd3 == bd) { fi = min(fi, f3); la = max(la, l3); }

    red_d[slice][lane] = bd;
    red_f[slice][lane] = fi;
    red_l[slice][lane] = la;
    __syncthreads();

    if (t < QB) {
        float gb = red_d[0][t];
        #pragma unroll
        for (int s = 1; s < NSLICE; ++s) gb = fminf(gb, red_d[s][t]);
        int gf = 0x7FFFFFFF, gl = -1;
        #pragma unroll
        for (int s = 0; s < NSLICE; ++s) {
            if (red_d[s][t] == gb) {
                gf = min(gf, red_f[s][t]);
                gl = max(gl, red_l[s][t]);
            }
        }
        int span = gl - gf;
        int idx  = (span > 1200) ? gl : gf;

        int q2 = qg * QB + t;
        size_t o = (size_t)b * NPTS + q2;
        const size_t SEG = (size_t)BATCH * NPTS;   // 32768
        out[(size_t)dir * SEG + o]           = gb;
        out[2 * SEG + (size_t)dir * SEG + o] = (float)idx;
    }
}

extern "C" void kernel_launch(void* const* d_in, const int* in_sizes, int n_in,
                              void* d_out, int out_size, void* d_ws, size_t ws_size,
                              hipStream_t stream) {
    const float* xyz1 = (const float*)d_in[0];
    const float* xyz2 = (const float*)d_in[1];
    float* out = (float*)d_out;
    float4* pk = (float4*)d_ws;                // 2*4*8192*16 B = 1 MiB

    prep_k<<<(2 * BATCH * NPTS) / 256, 256, 0, stream>>>(xyz1, xyz2, pk);
    chamfer_main<<<2 * BATCH * (NPTS / QB), 256, 0, stream>>>(pk, out);
}

// Round 19
// 404.731 us; speedup vs baseline: 1.1190x; 1.1190x over previous
//
#include <hip/hip_runtime.h>
#include <math.h>

// Chamfer distance, B=4, N=M=8192, fp32. Semantics validated R15-R18.
// d_out (f32): dist1[B*N] | dist2[B*M] | idx1[B*N] | idx2[B*M]
//
// Exact per-pair math (no FMA, validated):
//   qq/tt = (x*x+y*y)+z*z ; e = (qz*z+qy*y)+qx*x ; sq = (qq+tt)-2.0f*e
//   d = sqrtf(max(sq,0)) ; track FIRST and LAST index of min-d;
//   idx = (last-first>1200) ? last : first.
//
// R19: 1 query/thread, 8-way target split, whole-chunk LDS staging (one
// barrier), 4 independent residue accumulators, 100%-occupancy config.

#define BATCH 4
#define NPTS  8192
#define SPLIT 8
#define CHUNK 1024              // targets per split
#define NQ    65536             // total query slots (2*4*8192)

__global__ __launch_bounds__(256, 8)
void chamfer_part(const float* __restrict__ xyz1,
                  const float* __restrict__ xyz2,
                  float* __restrict__ ws_bd,
                  unsigned* __restrict__ ws_fl) {
#pragma clang fp contract(off)
    __shared__ float4 tile[CHUNK];         // 16 KB

    int bid  = blockIdx.x;                 // qgrp*8 + s
    int s    = bid & 7;
    int qgrp = bid >> 3;                   // 0..255
    int g    = qgrp & 31;                  // query sub-group within (dir,b)
    int db   = qgrp >> 5;
    int b    = db & 3;
    int dir  = db >> 2;

    const float* Q = (dir == 0) ? xyz1 : xyz2;
    const float* T = (dir == 0) ? xyz2 : xyz1;

    int t  = threadIdx.x;
    int qi = g * 256 + t;                  // my query within (dir,b)

    const float* qp = Q + ((size_t)b * NPTS + qi) * 3;
    float qx = qp[0], qy = qp[1], qz = qp[2];
    float qq = __fadd_rn(__fadd_rn(__fmul_rn(qx, qx), __fmul_rn(qy, qy)),
                         __fmul_rn(qz, qz));

    // stage CHUNK targets: 4 points (3 float4) per thread, coalesced
    {
        const float* Tb = T + ((size_t)b * NPTS + (size_t)s * CHUNK) * 3;
        const float4* src = reinterpret_cast<const float4*>(Tb) + (size_t)t * 3;
        float4 A = src[0];                 // x0 y0 z0 x1
        float4 Bv = src[1];                // y1 z1 x2 y2
        float4 C = src[2];                 // z2 x3 y3 z3
        int p4 = t * 4;
        {
            float x = A.x, y = A.y, z = A.z;
            float tt = __fadd_rn(__fadd_rn(__fmul_rn(x, x), __fmul_rn(y, y)), __fmul_rn(z, z));
            tile[p4 + 0] = make_float4(x, y, z, tt);
        }
        {
            float x = A.w, y = Bv.x, z = Bv.y;
            float tt = __fadd_rn(__fadd_rn(__fmul_rn(x, x), __fmul_rn(y, y)), __fmul_rn(z, z));
            tile[p4 + 1] = make_float4(x, y, z, tt);
        }
        {
            float x = Bv.z, y = Bv.w, z = C.x;
            float tt = __fadd_rn(__fadd_rn(__fmul_rn(x, x), __fmul_rn(y, y)), __fmul_rn(z, z));
            tile[p4 + 2] = make_float4(x, y, z, tt);
        }
        {
            float x = C.y, y = C.z, z = C.w;
            float tt = __fadd_rn(__fadd_rn(__fmul_rn(x, x), __fmul_rn(y, y)), __fmul_rn(z, z));
            tile[p4 + 3] = make_float4(x, y, z, tt);
        }
    }
    __syncthreads();

    float bd0 = INFINITY, bd1 = INFINITY, bd2 = INFINITY, bd3 = INFINITY;
    int f0 = 0, f1 = 0, f2 = 0, f3 = 0;
    int l0 = 0, l1 = 0, l2 = 0, l3 = 0;

    // 4 independent residue chains; 4 broadcast b128 loads per group
    #define POINT(V, JI, BD, FF, LL)                                        \
    {                                                                       \
        float m1 = __fmul_rn(qz, V.z);                                      \
        float m2 = __fmul_rn(qy, V.y);                                      \
        float a1 = __fadd_rn(m1, m2);                                       \
        float m3 = __fmul_rn(qx, V.x);                                      \
        float e  = __fadd_rn(a1, m3);                                       \
        float ss = __fadd_rn(qq, V.w);                                      \
        float e2 = __fmul_rn(2.0f, e);                                      \
        float qs = __fsub_rn(ss, e2);                                       \
        float c  = fmaxf(qs, 0.0f);                                         \
        float d  = sqrtf(c);                                                \
        bool lt = d < BD, le = d <= BD;                                     \
        FF = lt ? (JI) : FF; LL = le ? (JI) : LL; BD = fminf(BD, d);        \
    }

    #pragma unroll 2
    for (int j = 0; j < CHUNK; j += 4) {
        float4 v0 = tile[j + 0];
        float4 v1 = tile[j + 1];
        float4 v2 = tile[j + 2];
        float4 v3 = tile[j + 3];
        POINT(v0, j + 0, bd0, f0, l0)
        POINT(v1, j + 1, bd1, f1, l1)
        POINT(v2, j + 2, bd2, f2, l2)
        POINT(v3, j + 3, bd3, f3, l3)
    }
    #undef POINT

    // union-merge 4 residues (validated semantics)
    float bd = fminf(fminf(bd0, bd1), fminf(bd2, bd3));
    int fi = 0x7FFFFFFF, la = -1;
    if (bd0 == bd) { fi = min(fi, f0); la = max(la, l0); }
    if (bd1 == bd) { fi = min(fi, f1); la = max(la, l1); }
    if (bd2 == bd) { fi = min(fi, f2); la = max(la, l2); }
    if (bd3 == bd) { fi = min(fi, f3); la = max(la, l3); }

    // globalize indices and store partial
    int jbase = s * CHUNK;
    unsigned fg = (unsigned)(jbase + fi);
    unsigned lg = (unsigned)(jbase + la);
    int qidx = (dir * BATCH + b) * NPTS + qi;      // 0..65535
    int slot = qidx * SPLIT + s;
    ws_bd[slot] = bd;
    ws_fl[slot] = fg | (lg << 13);                 // 13-bit packed indices
}

__global__ __launch_bounds__(256)
void chamfer_merge(const float* __restrict__ ws_bd,
                   const unsigned* __restrict__ ws_fl,
                   float* __restrict__ out) {
    int tid = blockIdx.x * blockDim.x + threadIdx.x;   // 0..65535
    int dir = tid >> 15;
    int rem = tid & 32767;

    float gb = INFINITY;
    #pragma unroll
    for (int s = 0; s < SPLIT; ++s) gb = fminf(gb, ws_bd[tid * SPLIT + s]);

    int gf = 0x7FFFFFFF, gl = -1;
    #pragma unroll
    for (int s = 0; s < SPLIT; ++s) {
        if (ws_bd[tid * SPLIT + s] == gb) {
            unsigned fl = ws_fl[tid * SPLIT + s];
            int f = (int)(fl & 0x1FFFu);
            int l = (int)(fl >> 13);
            gf = min(gf, f);
            gl = max(gl, l);
        }
    }

    int span = gl - gf;
    int idx  = (span > 1200) ? gl : gf;

    const size_t SEG = (size_t)BATCH * NPTS;   // 32768
    size_t o = (size_t)rem;
    out[(size_t)dir * SEG + o]           = gb;
    out[2 * SEG + (size_t)dir * SEG + o] = (float)idx;
}

extern "C" void kernel_launch(void* const* d_in, const int* in_sizes, int n_in,
                              void* d_out, int out_size, void* d_ws, size_t ws_size,
                              hipStream_t stream) {
    const float* xyz1 = (const float*)d_in[0];
    const float* xyz2 = (const float*)d_in[1];
    float* out = (float*)d_out;

    float*    ws_bd = (float*)d_ws;                                  // 2 MiB
    unsigned* ws_fl = (unsigned*)((char*)d_ws + (size_t)NQ * SPLIT * 4); // 2 MiB

    chamfer_part<<<256 * SPLIT, 256, 0, stream>>>(xyz1, xyz2, ws_bd, ws_fl);
    chamfer_merge<<<NQ / 256, 256, 0, stream>>>(ws_bd, ws_fl, out);
}

// Round 20
// 352.756 us; speedup vs baseline: 1.2839x; 1.1473x over previous
//
#include <hip/hip_runtime.h>
#include <math.h>

// Chamfer distance, B=4, N=M=8192, fp32. Semantics validated R15-R19.
// d_out (f32): dist1[B*N] | dist2[B*M] | idx1[B*N] | idx2[B*M]
//
// Exact per-pair math (no FMA, validated):
//   qq/tt = (x*x+y*y)+z*z ; e = (qz*z+qy*y)+qx*x ; sq = (qq+tt)-2.0f*e
//   d = sqrtf(max(sq,0)) ; track FIRST and LAST index of min-d;
//   idx = (last-first>1200) ? last : first.
//
// R20: 4 queries per lane -> each broadcast ds_read_b128 feeds 4 chains
// (LDS-pipe floor /4, ILP x4). 4 waves share 256 queries, split the staged
// 1024-target chunk 4-way; cross-wave union-merge in LDS; 8 splits -> ws;
// merge kernel applies union + span rule.

#define BATCH 4
#define NPTS  8192
#define CHUNK 1024
#define SPLIT 8                 // NPTS / CHUNK
#define NQ    65536

__global__ __launch_bounds__(256, 6)
void chamfer_part(const float* __restrict__ xyz1,
                  const float* __restrict__ xyz2,
                  float* __restrict__ ws_bd,
                  unsigned* __restrict__ ws_fl) {
#pragma clang fp contract(off)
    __shared__ float4   tile[CHUNK];       // 16 KB {x,y,z,tt}
    __shared__ float    red_bd[4][256];    // 4 KB
    __shared__ unsigned red_fl[4][256];    // 4 KB  f | l<<13 (local-global 13b)

    int bid  = blockIdx.x;                 // dir*1024 + b*256 + qblk*8 + s
    int s    = bid & 7;
    int qblk = (bid >> 3) & 31;
    int b    = (bid >> 8) & 3;
    int dir  = bid >> 10;

    const float* Q = (dir == 0) ? xyz1 : xyz2;
    const float* T = (dir == 0) ? xyz2 : xyz1;

    int t    = threadIdx.x;
    int lane = t & 63;
    int wv   = t >> 6;

    // ---- stage CHUNK targets: 4 points (3 float4) per thread, coalesced ----
    {
        const float* Tb = T + ((size_t)b * NPTS + (size_t)s * CHUNK) * 3;
        const float4* src = reinterpret_cast<const float4*>(Tb) + (size_t)t * 3;
        float4 A = src[0];                 // x0 y0 z0 x1
        float4 Bv = src[1];                // y1 z1 x2 y2
        float4 C = src[2];                 // z2 x3 y3 z3
        int p4 = t * 4;
        {
            float x = A.x, y = A.y, z = A.z;
            float tt = __fadd_rn(__fadd_rn(__fmul_rn(x, x), __fmul_rn(y, y)), __fmul_rn(z, z));
            tile[p4 + 0] = make_float4(x, y, z, tt);
        }
        {
            float x = A.w, y = Bv.x, z = Bv.y;
            float tt = __fadd_rn(__fadd_rn(__fmul_rn(x, x), __fmul_rn(y, y)), __fmul_rn(z, z));
            tile[p4 + 1] = make_float4(x, y, z, tt);
        }
        {
            float x = Bv.z, y = Bv.w, z = C.x;
            float tt = __fadd_rn(__fadd_rn(__fmul_rn(x, x), __fmul_rn(y, y)), __fmul_rn(z, z));
            tile[p4 + 2] = make_float4(x, y, z, tt);
        }
        {
            float x = C.y, y = C.z, z = C.w;
            float tt = __fadd_rn(__fadd_rn(__fmul_rn(x, x), __fmul_rn(y, y)), __fmul_rn(z, z));
            tile[p4 + 3] = make_float4(x, y, z, tt);
        }
    }

    // ---- my 4 queries: q_k = qblk*256 + k*64 + lane ----
    float qx[4], qy[4], qz[4], qq[4];
    {
        const float* Qb = Q + (size_t)b * NPTS * 3;
        #pragma unroll
        for (int k = 0; k < 4; ++k) {
            int qi = qblk * 256 + k * 64 + lane;
            const float* qp = Qb + (size_t)qi * 3;
            float x = qp[0], y = qp[1], z = qp[2];
            qx[k] = x; qy[k] = y; qz[k] = z;
            qq[k] = __fadd_rn(__fadd_rn(__fmul_rn(x, x), __fmul_rn(y, y)),
                              __fmul_rn(z, z));
        }
    }

    float bd[4] = {INFINITY, INFINITY, INFINITY, INFINITY};
    int   ff[4] = {0, 0, 0, 0};
    int   ll[4] = {0, 0, 0, 0};

    __syncthreads();

    // ---- compute: wave wv scans chunk range [wv*256, wv*256+256) ----
    const float4* wt = tile + wv * 256;

    #define POINT(V, JI, K)                                                 \
    {                                                                       \
        float m1 = __fmul_rn(qz[K], V.z);                                   \
        float m2 = __fmul_rn(qy[K], V.y);                                   \
        float a1 = __fadd_rn(m1, m2);                                       \
        float m3 = __fmul_rn(qx[K], V.x);                                   \
        float e  = __fadd_rn(a1, m3);                                       \
        float ss = __fadd_rn(qq[K], V.w);                                   \
        float e2 = __fmul_rn(2.0f, e);                                      \
        float qs = __fsub_rn(ss, e2);                                       \
        float c  = fmaxf(qs, 0.0f);                                         \
        float d  = sqrtf(c);                                                \
        bool lt = d < bd[K], le = d <= bd[K];                               \
        ff[K] = lt ? (JI) : ff[K];                                          \
        ll[K] = le ? (JI) : ll[K];                                          \
        bd[K] = fminf(bd[K], d);                                            \
    }

    #pragma unroll 2
    for (int j = 0; j < 256; j += 2) {
        float4 v0 = wt[j + 0];
        float4 v1 = wt[j + 1];
        #pragma unroll
        for (int k = 0; k < 4; ++k) POINT(v0, j + 0, k)
        #pragma unroll
        for (int k = 0; k < 4; ++k) POINT(v1, j + 1, k)
    }
    #undef POINT

    // ---- write per-wave partials (global 13-bit indices) ----
    int jg = s * CHUNK + wv * 256;
    #pragma unroll
    for (int k = 0; k < 4; ++k) {
        int qs = k * 64 + lane;            // 0..255  == query offset in block
        red_bd[wv][qs] = bd[k];
        red_fl[wv][qs] = (unsigned)(jg + ff[k]) | ((unsigned)(jg + ll[k]) << 13);
    }
    __syncthreads();

    // ---- cross-wave union merge: thread t owns query-slot t ----
    {
        float gb = red_bd[0][t];
        #pragma unroll
        for (int w = 1; w < 4; ++w) gb = fminf(gb, red_bd[w][t]);
        int gf = 0x7FFFFFFF, gl = -1;
        #pragma unroll
        for (int w = 0; w < 4; ++w) {
            if (red_bd[w][t] == gb) {
                unsigned fl = red_fl[w][t];
                int f = (int)(fl & 0x1FFFu);
                int l = (int)(fl >> 13);
                gf = min(gf, f);
                gl = max(gl, l);
            }
        }
        int qidx = (dir * BATCH + b) * NPTS + qblk * 256 + t;   // 0..65535
        int slot = qidx * SPLIT + s;
        ws_bd[slot] = gb;
        ws_fl[slot] = (unsigned)gf | ((unsigned)gl << 13);
    }
}

__global__ __launch_bounds__(256)
void chamfer_merge(const float* __restrict__ ws_bd,
                   const unsigned* __restrict__ ws_fl,
                   float* __restrict__ out) {
    int tid = blockIdx.x * blockDim.x + threadIdx.x;   // 0..65535
    int dir = tid >> 15;
    int rem = tid & 32767;

    float gb = INFINITY;
    #pragma unroll
    for (int s = 0; s < SPLIT; ++s) gb = fminf(gb, ws_bd[tid * SPLIT + s]);

    int gf = 0x7FFFFFFF, gl = -1;
    #pragma unroll
    for (int s = 0; s < SPLIT; ++s) {
        if (ws_bd[tid * SPLIT + s] == gb) {
            unsigned fl = ws_fl[tid * SPLIT + s];
            int f = (int)(fl & 0x1FFFu);
            int l = (int)(fl >> 13);
            gf = min(gf, f);
            gl = max(gl, l);
        }
    }

    int span = gl - gf;
    int idx  = (span > 1200) ? gl : gf;

    const size_t SEG = (size_t)BATCH * NPTS;   // 32768
    size_t o = (size_t)rem;
    out[(size_t)dir * SEG + o]           = gb;
    out[2 * SEG + (size_t)dir * SEG + o] = (float)idx;
}

extern "C" void kernel_launch(void* const* d_in, const int* in_sizes, int n_in,
                              void* d_out, int out_size, void* d_ws, size_t ws_size,
                              hipStream_t stream) {
    const float* xyz1 = (const float*)d_in[0];
    const float* xyz2 = (const float*)d_in[1];
    float* out = (float*)d_out;

    float*    ws_bd = (float*)d_ws;                                   // 2 MiB
    unsigned* ws_fl = (unsigned*)((char*)d_ws + (size_t)NQ * SPLIT * 4); // 2 MiB

    chamfer_part<<<2048, 256, 0, stream>>>(xyz1, xyz2, ws_bd, ws_fl);
    chamfer_merge<<<NQ / 256, 256, 0, stream>>>(ws_bd, ws_fl, out);
}